// Round 3
// baseline (8748.767 us; speedup 1.0000x reference)
//
#include <hip/hip_runtime.h>

// TextDecoder: 2-layer LSTM, B=64, H=1024, V=10000, T=32 (31 computed steps).
// Round 4: persistent kernel, 256 blocks x 512 threads (8 waves/CU, 2/SIMD;
// VGPR cap 256 so the MFMA loop cannot spill — the 1024-thread round forced
// <=128 VGPR and likely spilled/hung). Grid barrier = the counter barrier that
// PASSED on hardware in the round-1 run, verbatim.
// Phases/step (4 barriers): P1 fused [logits-sum(t-1) + out-write + argmax +
// cell0] by 64 per-row blocks | P2 L1 gemms (2048 wave jobs) | P3 cell1 |
// P4 logits gemm (1256 jobs) + L0 gemm for t+1 (512 double jobs).
// Epilogue sums t=31 logits. Weight conversion + init = phase 0.

#define HDIM 1024
#define BDIM 64
#define VDIM 10000
#define VPAD 10048   // 314 * 32
#define TDIM 32
#define NB   256
#define BS   512

typedef _Float16 f16;
typedef _Float16 f16x8 __attribute__((ext_vector_type(8)));
typedef _Float16 f16x4 __attribute__((ext_vector_type(4)));
typedef float f32x4 __attribute__((ext_vector_type(4)));

// ---- workspace layout (bytes); total 96,735,232 <= proven ws_size (>=101,450,752)
#define WS_C1    0              // 64x1024 f32
#define WS_C2    262144
#define WS_H1H   524288         // 64x1024 f16 each
#define WS_H1L   655360
#define WS_H2H   786432
#define WS_H2L   917504
#define WS_PRE0  1048576        // 4 slabs x [64x4096] f32 (L0 partials, KS=4)
#define WS_PRE1  5242880        // 8 slabs x [64x4096] f32 (L1 partials)
                                //   aliased in P4/P1 by logits: 2 x [64xVPAD] f32
#define WS_BAR   13631488       // 256 B barrier state (memset 0 per call)
#define WS_WB    13635584       // converted weights
#define SQB      8388608        // one 4096x1024 f16 square

__device__ __forceinline__ float sigmoidf_(float x) {
    return 1.0f / (1.0f + expf(-x));
}

// Counter grid barrier — EXACT code that passed on HW in the round-1 bench.
// cnt at bar[0], generation at bar[32] (128 B apart).
__device__ __forceinline__ void gridbar(int* bar) {
    __syncthreads();
    if (threadIdx.x == 0) {
        __threadfence();
        int g = __hip_atomic_load(bar + 32, __ATOMIC_RELAXED, __HIP_MEMORY_SCOPE_AGENT);
        int a = __hip_atomic_fetch_add(bar, 1, __ATOMIC_ACQ_REL, __HIP_MEMORY_SCOPE_AGENT);
        if (a == NB - 1) {
            __hip_atomic_store(bar, 0, __ATOMIC_RELAXED, __HIP_MEMORY_SCOPE_AGENT);
            __hip_atomic_fetch_add(bar + 32, 1, __ATOMIC_RELEASE, __HIP_MEMORY_SCOPE_AGENT);
        } else {
            while (__hip_atomic_load(bar + 32, __ATOMIC_ACQUIRE, __HIP_MEMORY_SCOPE_AGENT) == g)
                __builtin_amdgcn_s_sleep(4);
        }
    }
    __syncthreads();
}

// ------------------------------------------------------------------
// Per-wave 32x32 split-fp16 MFMA GEMM job over k in [kbase, kbase+klen).
// A rows m0..m0+31 (hi+lo), W rows n0..n0+31 (lo only if WSPLIT).
// C layout (HW-verified): row = m0 + rt*16 + quad*4 + r, col = n0 + ct*16 + lm.
// ------------------------------------------------------------------
template <bool WSPLIT>
__device__ __forceinline__ void wgemm(
    const f16* __restrict__ Ah, const f16* __restrict__ Al,
    const f16* __restrict__ Wh, const f16* __restrict__ Wl,
    int m0, int n0, int kbase, int klen, float* __restrict__ dst, int ldd)
{
    const int lane = threadIdx.x & 63;
    const int lm = lane & 15, quad = lane >> 4;
    f32x4 acc[2][2] = {};
    f32x4 accL[2][2] = {};
    const f16* a_h = Ah + (size_t)(m0 + lm) * HDIM + kbase + quad * 8;
    const f16* a_l = Al + (size_t)(m0 + lm) * HDIM + kbase + quad * 8;
    const f16* b_h = Wh + (size_t)(n0 + lm) * HDIM + kbase + quad * 8;
    const f16* b_l = WSPLIT ? (Wl + (size_t)(n0 + lm) * HDIM + kbase + quad * 8)
                            : (const f16*)nullptr;
    #pragma unroll 2
    for (int ko = 0; ko < klen; ko += 32) {
        f16x8 ah0 = *(const f16x8*)(a_h + ko);
        f16x8 ah1 = *(const f16x8*)(a_h + 16 * HDIM + ko);
        f16x8 al0 = *(const f16x8*)(a_l + ko);
        f16x8 al1 = *(const f16x8*)(a_l + 16 * HDIM + ko);
        f16x8 bh0 = *(const f16x8*)(b_h + ko);
        f16x8 bh1 = *(const f16x8*)(b_h + 16 * HDIM + ko);

        acc[0][0] = __builtin_amdgcn_mfma_f32_16x16x32_f16(ah0, bh0, acc[0][0], 0, 0, 0);
        acc[0][1] = __builtin_amdgcn_mfma_f32_16x16x32_f16(ah0, bh1, acc[0][1], 0, 0, 0);
        acc[1][0] = __builtin_amdgcn_mfma_f32_16x16x32_f16(ah1, bh0, acc[1][0], 0, 0, 0);
        acc[1][1] = __builtin_amdgcn_mfma_f32_16x16x32_f16(ah1, bh1, acc[1][1], 0, 0, 0);

        accL[0][0] = __builtin_amdgcn_mfma_f32_16x16x32_f16(al0, bh0, accL[0][0], 0, 0, 0);
        accL[0][1] = __builtin_amdgcn_mfma_f32_16x16x32_f16(al0, bh1, accL[0][1], 0, 0, 0);
        accL[1][0] = __builtin_amdgcn_mfma_f32_16x16x32_f16(al1, bh0, accL[1][0], 0, 0, 0);
        accL[1][1] = __builtin_amdgcn_mfma_f32_16x16x32_f16(al1, bh1, accL[1][1], 0, 0, 0);

        if constexpr (WSPLIT) {
            f16x8 bl0 = *(const f16x8*)(b_l + ko);
            f16x8 bl1 = *(const f16x8*)(b_l + 16 * HDIM + ko);
            accL[0][0] = __builtin_amdgcn_mfma_f32_16x16x32_f16(ah0, bl0, accL[0][0], 0, 0, 0);
            accL[0][1] = __builtin_amdgcn_mfma_f32_16x16x32_f16(ah0, bl1, accL[0][1], 0, 0, 0);
            accL[1][0] = __builtin_amdgcn_mfma_f32_16x16x32_f16(ah1, bl0, accL[1][0], 0, 0, 0);
            accL[1][1] = __builtin_amdgcn_mfma_f32_16x16x32_f16(ah1, bl1, accL[1][1], 0, 0, 0);
        }
    }
    #pragma unroll
    for (int rt = 0; rt < 2; rt++)
        #pragma unroll
        for (int ct = 0; ct < 2; ct++)
            #pragma unroll
            for (int r = 0; r < 4; r++) {
                int row = m0 + rt * 16 + quad * 4 + r;
                int col = n0 + ct * 16 + lm;
                dst[(size_t)row * ldd + col] =
                    acc[rt][ct][r] + accL[rt][ct][r] * (1.0f / 2048.0f);
            }
}

__device__ __forceinline__ void convsq_hi(const float* __restrict__ src,
                                          f16* __restrict__ hi, int gt)
{
    const float4* s4 = (const float4*)src;
    f16x4* h4 = (f16x4*)hi;
    for (int i = gt; i < 4096 * HDIM / 4; i += NB * BS) {
        float4 v = s4[i];
        f16x4 H = {(f16)v.x, (f16)v.y, (f16)v.z, (f16)v.w};
        h4[i] = H;
    }
}

__device__ __forceinline__ void convsq_split(const float* __restrict__ src,
                                             f16* __restrict__ hi,
                                             f16* __restrict__ lo, int gt)
{
    const float4* s4 = (const float4*)src;
    f16x4* h4 = (f16x4*)hi;
    f16x4* l4 = (f16x4*)lo;
    for (int i = gt; i < 4096 * HDIM / 4; i += NB * BS) {
        float4 v = s4[i];
        f16 a = (f16)v.x, b = (f16)v.y, c = (f16)v.z, d = (f16)v.w;
        f16x4 H = {a, b, c, d};
        f16x4 L = {(f16)((v.x - (float)a) * 2048.0f), (f16)((v.y - (float)b) * 2048.0f),
                   (f16)((v.z - (float)c) * 2048.0f), (f16)((v.w - (float)d) * 2048.0f)};
        h4[i] = H;
        l4[i] = L;
    }
}

__global__ __launch_bounds__(BS) void decode_all(
    const float* __restrict__ hidden, const float* __restrict__ cellin,
    const int* __restrict__ captions, const int* __restrict__ tfmask,
    const float* __restrict__ Wih0, const float* __restrict__ Whh0,
    const float* __restrict__ bih0, const float* __restrict__ bhh0,
    const float* __restrict__ Wih1, const float* __restrict__ Whh1,
    const float* __restrict__ bih1, const float* __restrict__ bhh1,
    const float* __restrict__ Wout, const float* __restrict__ bout,
    float* __restrict__ out, char* __restrict__ wsb)
{
    const int tid = threadIdx.x, bid = blockIdx.x;
    const int jslot = (tid >> 6) * NB + bid;   // wave-job slot, 0..2047

    float* c1 = (float*)(wsb + WS_C1);
    float* c2 = (float*)(wsb + WS_C2);
    f16* h1h = (f16*)(wsb + WS_H1H);
    f16* h1l = (f16*)(wsb + WS_H1L);
    f16* h2h = (f16*)(wsb + WS_H2H);
    f16* h2l = (f16*)(wsb + WS_H2L);
    float* pre0 = (float*)(wsb + WS_PRE0);
    float* pre1 = (float*)(wsb + WS_PRE1);
    float* logb = (float*)(wsb + WS_PRE1);     // aliases pre1 (dead by P4)
    int* bar = (int*)(wsb + WS_BAR);
    f16* Whh0h = (f16*)(wsb + WS_WB);
    f16* Wih1h = (f16*)(wsb + WS_WB + 1 * (size_t)SQB);
    f16* Wih1l = (f16*)(wsb + WS_WB + 2 * (size_t)SQB);
    f16* Whh1h = (f16*)(wsb + WS_WB + 3 * (size_t)SQB);
    f16* Whh1l = (f16*)(wsb + WS_WB + 4 * (size_t)SQB);
    f16* Wouth = (f16*)(wsb + WS_WB + 5 * (size_t)SQB);
    f16* Woutl = (f16*)(wsb + WS_WB + 5 * (size_t)SQB + (size_t)VPAD * HDIM * 2);

    __shared__ unsigned long long red_s[8];
    __shared__ int tok_s;

    // ---------------- phase 0: weight conversion + state init ----------------
    {
        const int gt = bid * BS + tid;
        convsq_hi(Whh0, Whh0h, gt);
        convsq_split(Wih1, Wih1h, Wih1l, gt);
        convsq_split(Whh1, Whh1h, Whh1l, gt);
        {   // W_out hi+lo, zero-padded rows to VPAD
            const float4* s4 = (const float4*)Wout;
            f16x4* h4 = (f16x4*)Wouth;
            f16x4* l4 = (f16x4*)Woutl;
            for (int i = gt; i < VPAD * HDIM / 4; i += NB * BS) {
                float4 v = (i < VDIM * HDIM / 4) ? s4[i] : make_float4(0.f, 0.f, 0.f, 0.f);
                f16 a = (f16)v.x, b = (f16)v.y, c = (f16)v.z, d = (f16)v.w;
                f16x4 H = {a, b, c, d};
                f16x4 L = {(f16)((v.x - (float)a) * 2048.0f), (f16)((v.y - (float)b) * 2048.0f),
                           (f16)((v.z - (float)c) * 2048.0f), (f16)((v.w - (float)d) * 2048.0f)};
                h4[i] = H;
                l4[i] = L;
            }
        }
        for (int i = gt; i < BDIM * HDIM; i += NB * BS) {   // states
            float a = hidden[i], b = hidden[BDIM * HDIM + i];
            f16 ah = (f16)a, bh = (f16)b;
            h1h[i] = ah; h1l[i] = (f16)((a - (float)ah) * 2048.0f);
            h2h[i] = bh; h2l[i] = (f16)((b - (float)bh) * 2048.0f);
            c1[i] = cellin[i];
            c2[i] = cellin[BDIM * HDIM + i];
        }
        for (int i = gt; i < BDIM * VDIM; i += NB * BS) {   // out[:,0,:] one-hot
            int b = i / VDIM, v = i - b * VDIM;
            out[(size_t)b * (TDIM * VDIM) + v] = (v == captions[b * TDIM]) ? 1.0f : 0.0f;
        }
    }
    gridbar(bar);

    // ------------- prologue: L0 h-gemm for t=1 (1024 wave-jobs, KS=4) -------------
    if (jslot < 1024) {
        int q = jslot >> 8, w = jslot & 255;
        wgemm<false>(h1h, h1l, Whh0h, nullptr,
                     (w >> 7) * 32, (w & 127) * 32, q * 256, 256,
                     pre0 + (size_t)q * 262144, 4096);
    }
    gridbar(bar);

    for (int t = 1; t < TDIM; t++) {
        // ---- P1: fused logits-sum(t-1) + out + argmax + cell0 (64 row-blocks) ----
        if (bid < BDIM) {
            const int b = bid;
            int tok;
            if (t > 1) {
                const float* l0 = logb + (size_t)b * VPAD;
                const float* l1 = logb + (size_t)(64 * VPAD) + (size_t)b * VPAD;
                float* orow = out + (size_t)b * (TDIM * VDIM) + (size_t)(t - 1) * VDIM;
                unsigned long long best = 0ull;
                for (int c = tid; c < VDIM; c += BS) {
                    float sv = l0[c] + l1[c] + bout[c];
                    orow[c] = sv;
                    unsigned u = __float_as_uint(sv);
                    u = (u & 0x80000000u) ? ~u : (u | 0x80000000u);
                    unsigned long long p = ((unsigned long long)u << 32) | (unsigned)(~c);
                    if (p > best) best = p;
                }
                #pragma unroll
                for (int m = 32; m > 0; m >>= 1) {
                    unsigned long long o = __shfl_down(best, m, 64);
                    if (o > best) best = o;
                }
                if ((tid & 63) == 0) red_s[tid >> 6] = best;
                __syncthreads();
                if (tid == 0) {
                    best = red_s[0];
                    #pragma unroll
                    for (int w = 1; w < 8; w++) if (red_s[w] > best) best = red_s[w];
                    tok_s = (int)(~(unsigned)(best & 0xffffffffull));
                }
                __syncthreads();
                tok = (tfmask[t - 1] != 0) ? captions[b * TDIM + (t - 1)] : tok_s;
            } else {
                tok = captions[b * TDIM];
            }
            #pragma unroll
            for (int ii = 0; ii < 2; ii++) {
                int i = ii * BS + tid;
                float g[4];
                #pragma unroll
                for (int gi = 0; gi < 4; gi++) {
                    int j = (gi << 10) + i;
                    float s = bih0[j] + bhh0[j] + Wih0[(size_t)j * VDIM + tok];
                    #pragma unroll
                    for (int q = 0; q < 4; q++) s += pre0[q * 262144 + (b << 12) + j];
                    g[gi] = s;
                }
                int idx = (b << 10) + i;
                float ig = sigmoidf_(g[0]), fg = sigmoidf_(g[1]);
                float gg = tanhf(g[2]),     og = sigmoidf_(g[3]);
                float cn = fg * c1[idx] + ig * gg;
                float hn = og * tanhf(cn);
                c1[idx] = cn;
                f16 hh = (f16)hn;
                h1h[idx] = hh;
                h1l[idx] = (f16)((hn - (float)hh) * 2048.0f);
            }
        }
        gridbar(bar);

        // ---- P2: layer-1 GEMMs (z=0: h1@Wih1, z=1: h2@Whh1), 2048 wave-jobs ----
        {
            int z = jslot >> 10, r = jslot & 1023;
            int q = r >> 8, w = r & 255;
            const f16* Ah = z ? h2h : h1h;
            const f16* Al = z ? h2l : h1l;
            const f16* Wh = z ? Whh1h : Wih1h;
            const f16* Wl = z ? Whh1l : Wih1l;
            wgemm<true>(Ah, Al, Wh, Wl, (w >> 7) * 32, (w & 127) * 32,
                        q * 256, 256, pre1 + (size_t)((z << 2) + q) * 262144, 4096);
        }
        gridbar(bar);

        // ---- P3: cell1 (256 blocks x 256 active threads, 1 element each) ----
        if (tid < 256) {
            int e = (bid << 8) + tid;          // 0..65535
            int b = e >> 10, i = e & 1023;
            float g[4];
            #pragma unroll
            for (int gi = 0; gi < 4; gi++) {
                int j = (gi << 10) + i;
                float s = bih1[j] + bhh1[j];
                #pragma unroll
                for (int q = 0; q < 8; q++) s += pre1[q * 262144 + (b << 12) + j];
                g[gi] = s;
            }
            float ig = sigmoidf_(g[0]), fg = sigmoidf_(g[1]);
            float gg = tanhf(g[2]),     og = sigmoidf_(g[3]);
            float cn = fg * c2[e] + ig * gg;
            float hn = og * tanhf(cn);
            c2[e] = cn;
            f16 hh = (f16)hn;
            h2h[e] = hh;
            h2l[e] = (f16)((hn - (float)hh) * 2048.0f);
        }
        gridbar(bar);

        // ---- P4: logits KS=2 (1256 jobs) || L0 gemm for t+1 (512 double jobs) ----
        if (jslot < 1256) {
            int w = jslot >> 1, q = jslot & 1;
            int mt = (w >= 314) ? 1 : 0;
            int nt = w - mt * 314;
            wgemm<true>(h2h, h2l, Wouth, Woutl, mt * 32, nt * 32,
                        q * 512, 512, logb + (size_t)q * (64 * VPAD), VPAD);
        } else if (jslot < 1768 && t < TDIM - 1) {
            int u = jslot - 1256;              // 0..511
            int q = u >> 7;                    // 0..3
            int w2 = u & 127;
            int m0 = (w2 >> 6) * 32;
            int nn = (w2 & 63) * 64;
            wgemm<false>(h1h, h1l, Whh0h, nullptr, m0, nn, q * 256, 256,
                         pre0 + (size_t)q * 262144, 4096);
            wgemm<false>(h1h, h1l, Whh0h, nullptr, m0, nn + 32, q * 256, 256,
                         pre0 + (size_t)q * 262144, 4096);
        }
        gridbar(bar);
    }

    // ---------------- epilogue: out[:,31,:] = logits(t=31) + bias ----------------
    for (int g = bid * BS + tid; g < BDIM * VDIM; g += NB * BS) {
        int b = g / VDIM, c = g - b * VDIM;
        out[(size_t)b * (TDIM * VDIM) + (size_t)(TDIM - 1) * VDIM + c] =
            logb[(size_t)b * VPAD + c] +
            logb[(size_t)(64 * VPAD) + (size_t)b * VPAD + c] + bout[c];
    }
}

extern "C" void kernel_launch(void* const* d_in, const int* in_sizes, int n_in,
                              void* d_out, int out_size, void* d_ws, size_t ws_size,
                              hipStream_t stream)
{
    const float* hidden   = (const float*)d_in[0];
    const float* cellin   = (const float*)d_in[1];
    const int*   captions = (const int*)d_in[2];
    const int*   tfmask   = (const int*)d_in[3];
    const float* Wih0 = (const float*)d_in[4];
    const float* Whh0 = (const float*)d_in[5];
    const float* bih0 = (const float*)d_in[6];
    const float* bhh0 = (const float*)d_in[7];
    const float* Wih1 = (const float*)d_in[8];
    const float* Whh1 = (const float*)d_in[9];
    const float* bih1 = (const float*)d_in[10];
    const float* bhh1 = (const float*)d_in[11];
    const float* Wout = (const float*)d_in[12];
    const float* bout = (const float*)d_in[13];

    char* wsb = (char*)d_ws;
    // zero barrier state (ws is re-poisoned each call)
    hipMemsetAsync(wsb + WS_BAR, 0, 256, stream);
    decode_all<<<NB, BS, 0, stream>>>(hidden, cellin, captions, tfmask,
                                      Wih0, Whh0, bih0, bhh0,
                                      Wih1, Whh1, bih1, bhh1,
                                      Wout, bout, (float*)d_out, wsb);
}